// Round 9
// baseline (492.845 us; speedup 1.0000x reference)
//
#include <hip/hip_runtime.h>
#include <hip/hip_bf16.h>

// Problem constants (fixed by the reference)
#define NN 100000
#define NE 1600000
#define NG 64
#define FD 64
#define EPSV 1e-5f

typedef __hip_bfloat16 bf16;
typedef __attribute__((ext_vector_type(8))) short bf16x8;  // 8 bf16 = 4 VGPRs (MFMA A/B frag)
typedef __attribute__((ext_vector_type(4))) float f32x4;   // MFMA C/D frag

__device__ __forceinline__ float ldb(bf16 v) { return __bfloat162float(v); }
__device__ __forceinline__ bf16 f2b(float v) { return __float2bfloat16(v); }
__device__ __forceinline__ float b2f_bits(short s) {   // exact bf16 -> fp32
    return __uint_as_float(((unsigned)(unsigned short)s) << 16);
}

// ---------------- workspace layout (bytes) ----------------
// Atomic/scattered-write passes cost ~64-128B line traffic per op (R5/R6 measured; R9
// theory: scatter RMW). Pipeline: count(+u8 ticket) -> scan -> nt-scatter -> degdis ->
// rescale -> hops (csr.y = w*dis[src]; dis[dst] applied at row end).
constexpr size_t ALGN(size_t x) { return (x + 255) & ~(size_t)255; }
constexpr size_t OFF_CNT  = 0;                                         // int[NN] (zeroed)
constexpr size_t OFF_GSUM = OFF_CNT  + ALGN((size_t)NN * 4);           // float[NG*FD]
constexpr size_t OFF_GSSQ = OFF_GSUM + ALGN((size_t)NG * FD * 4);      // float[NG*FD]
constexpr size_t OFF_GCNT = OFF_GSSQ + ALGN((size_t)NG * FD * 4);      // float[NG]
constexpr size_t OFF_PSUM = OFF_GCNT + ALGN((size_t)NG * 4);           // float[NG*FD]
constexpr size_t OFF_PMAX = OFF_PSUM + ALGN((size_t)NG * FD * 4);      // int[NG*FD] (relu>=0 so 0-init ok)
constexpr size_t ZERO_BYTES = OFF_PMAX + ALGN((size_t)NG * FD * 4);    // everything above memset(0)
constexpr size_t OFF_GMEAN = ZERO_BYTES;                               // float[NG*FD]
constexpr size_t OFF_GRSTD = OFF_GMEAN + ALGN((size_t)NG * FD * 4);    // float[NG*FD]
constexpr size_t OFF_DIS   = OFF_GRSTD + ALGN((size_t)NG * FD * 4);    // float[NN]
constexpr size_t OFF_ROWP  = OFF_DIS   + ALGN((size_t)NN * 4);         // int[NN]
constexpr size_t OFF_BSUM  = OFF_ROWP  + ALGN((size_t)NN * 4);         // int[64]
constexpr size_t OFF_WT    = OFF_BSUM  + ALGN(64 * 4);                 // bf16[64][256] W^T stacked
constexpr size_t OFF_CSR   = OFF_WT    + ALGN(16384 * 2);              // int2[NE] {src, w/norm-bits}
constexpr size_t OFF_H     = OFF_CSR   + ALGN((size_t)NE * 8);         // bf16[NN][256]  x|h1|h2|h3
constexpr size_t OFF_TICK  = OFF_H;                                    // u8[NE] ALIAS: tick dead before xcopy writes H
constexpr size_t OFF_OUT   = OFF_H     + ALGN((size_t)NN * 256 * 2);   // float[NN*FD]

// ---------------- prep kernels ----------------

// ONE atomic per edge; returned old value = unique within-dst ticket (max degree << 255).
__global__ __launch_bounds__(256) void count_kernel(const int* __restrict__ dst,
                                                    int* __restrict__ cnts,
                                                    unsigned char* __restrict__ tick) {
    int e = blockIdx.x * 256 + threadIdx.x;
    if (e >= NE) return;
    unsigned char t = (unsigned char)atomicAdd(&cnts[dst[e]], 1);
    __builtin_nontemporal_store(t, &tick[e]);
}

#define SCAN_BLK 256
#define SCAN_ITEMS 8   // 2048 elems per block
__global__ __launch_bounds__(SCAN_BLK) void scan_blocks(const int* __restrict__ cnts,
                                                        int* __restrict__ rowp,
                                                        int* __restrict__ bsum) {
    __shared__ int lds[SCAN_BLK];
    int t = threadIdx.x, b = blockIdx.x;
    int base = b * SCAN_BLK * SCAN_ITEMS + t * SCAN_ITEMS;
    int v[SCAN_ITEMS];
    int s = 0;
    #pragma unroll
    for (int i = 0; i < SCAN_ITEMS; i++) {
        int idx = base + i;
        v[i] = (idx < NN) ? cnts[idx] : 0;
        s += v[i];
    }
    lds[t] = s;
    __syncthreads();
    for (int off = 1; off < SCAN_BLK; off <<= 1) {
        int x = (t >= off) ? lds[t - off] : 0;
        __syncthreads();
        lds[t] += x;
        __syncthreads();
    }
    int excl = lds[t] - s;
    if (t == SCAN_BLK - 1) bsum[b] = lds[t];
    int run = excl;
    #pragma unroll
    for (int i = 0; i < SCAN_ITEMS; i++) {
        int idx = base + i;
        if (idx < NN) rowp[idx] = run;
        run += v[i];
    }
}

__global__ void scan_sums(int* __restrict__ bsum, int nb) {
    if (threadIdx.x == 0 && blockIdx.x == 0) {
        int run = 0;
        for (int i = 0; i < nb; i++) { int t = bsum[i]; bsum[i] = run; run += t; }
    }
}

__global__ __launch_bounds__(256) void scan_add(int* __restrict__ rowp, const int* __restrict__ bsum) {
    int n = blockIdx.x * 256 + threadIdx.x;
    if (n >= NN) return;
    rowp[n] += bsum[n >> 11];
}

// atomic-free scatter: pos = rowp[dst] + tick. Stores RAW weight bits (rescaled later).
// NON-TEMPORAL single 8B store: bypass write-allocate RMW (R9 experiment).
__global__ __launch_bounds__(256) void scatter_kernel(const int* __restrict__ src,
                                                      const int* __restrict__ dst,
                                                      const float* __restrict__ ew,
                                                      const int* __restrict__ rowp,
                                                      const unsigned char* __restrict__ tick,
                                                      int2* __restrict__ csr) {
    int e = blockIdx.x * 256 + threadIdx.x;
    if (e >= NE) return;
    int d = dst[e];
    int pos = rowp[d] + (int)tick[e];
    // little-endian: low word -> .x (src), high word -> .y (w bits)
    unsigned long long v = ((unsigned long long)(unsigned)__float_as_int(ew[e]) << 32) |
                           (unsigned long long)(unsigned)src[e];
    __builtin_nontemporal_store(v, (unsigned long long*)&csr[pos]);
}

// deg[n] = sum of raw w over row n (atomic-free, rows are contiguous) ; dis = rsqrt
__global__ __launch_bounds__(256) void degdis_kernel(const int* __restrict__ rowp,
                                                     const int* __restrict__ cnts,
                                                     const int2* __restrict__ csr,
                                                     float* __restrict__ dis) {
    int n = blockIdx.x * 256 + threadIdx.x;
    if (n >= NN) return;
    int st = rowp[n], c = cnts[n];
    float s = 0.f;
    for (int j = 0; j < c; j++) s += __int_as_float(csr[st + j].y);
    dis[n] = (s > 0.f) ? rsqrtf(s) : 0.f;
}

// csr.y = w * dis[src]   (coalesced pass; dis is a 400KB L2-resident table)
__global__ __launch_bounds__(256) void rescale_kernel(int2* __restrict__ csr,
                                                      const float* __restrict__ dis) {
    int i = blockIdx.x * 256 + threadIdx.x;
    if (i >= NE) return;
    int2 e = csr[i];
    csr[i].y = __float_as_int(__int_as_float(e.y) * dis[e.x]);
}

// x (fp32) -> H[:, 0:64] (bf16, row stride 256)
__global__ __launch_bounds__(256) void xcopy_kernel(const float* __restrict__ x,
                                                    bf16* __restrict__ H) {
    int i = blockIdx.x * 256 + threadIdx.x;
    if (i >= NN * 64) return;
    int node = i >> 6, f = i & 63;
    H[(size_t)node * 256 + f] = f2b(x[(size_t)node * 64 + f]);
}

// W [4][64][64] fp32 (k-major) -> Wt[n][256] bf16
__global__ __launch_bounds__(256) void wt_kernel(const float* __restrict__ W,
                                                 bf16* __restrict__ Wt) {
    int i = blockIdx.x * 256 + threadIdx.x;  // 0..16383
    if (i >= 16384) return;
    int n = i & 63, kk = i >> 6;
    Wt[n * 256 + kk] = f2b(W[kk * 64 + n]);
}

// ---------------- hop: wide-vector gather ----------------
// One wave per dst row. 8 edges x 8 lanes x 16B: sub = lane>>3 picks the edge slot,
// fl = lane&7 picks the feature octet. Fast path (cnt<=24, ~98% of Poisson(16) rows):
// three predicated independent 8-edge groups. Heavy rows: 16-wide pipelined loop.
// Epilogue: 3 shfl_xor rounds reduce across sub; lanes sub==0 store coalesced bf16x8.
__global__ __launch_bounds__(256) void hop_kernel(const bf16* __restrict__ hin,  // H + 64*(k-1)
                                                  bf16* __restrict__ hout,       // H + 64*k
                                                  const int* __restrict__ rowp,
                                                  const int* __restrict__ cnts,
                                                  const int2* __restrict__ csr,
                                                  const float* __restrict__ dis) {
    int row = blockIdx.x * 4 + (threadIdx.x >> 6);
    if (row >= NN) return;
    row = __builtin_amdgcn_readfirstlane(row);
    int lane = threadIdx.x & 63;
    int sub = lane >> 3;   // edge slot 0..7
    int fl = lane & 7;     // feature octet 0..7
    int start = rowp[row];
    int cnt = cnts[row];
    float dr = dis[row];
    const int2* cp = csr + start;

    float a[8] = {0, 0, 0, 0, 0, 0, 0, 0};

    if (cnt <= 24) {
        int2 e0 = (sub < cnt) ? cp[sub] : make_int2(0, 0);
        int2 e1 = (8 + sub < cnt) ? cp[8 + sub] : make_int2(0, 0);
        int2 e2 = (16 + sub < cnt) ? cp[16 + sub] : make_int2(0, 0);
        bf16x8 v0 = *(const bf16x8*)(hin + (size_t)e0.x * 256 + fl * 8);
        bf16x8 v1 = *(const bf16x8*)(hin + (size_t)e1.x * 256 + fl * 8);
        bf16x8 v2 = *(const bf16x8*)(hin + (size_t)e2.x * 256 + fl * 8);
        float w0 = __int_as_float(e0.y);
        float w1 = __int_as_float(e1.y);
        float w2 = __int_as_float(e2.y);
        #pragma unroll
        for (int i = 0; i < 8; i++)
            a[i] = w0 * b2f_bits(v0[i]) + w1 * b2f_bits(v1[i]) + w2 * b2f_bits(v2[i]);
    } else {
        float b[8] = {0, 0, 0, 0, 0, 0, 0, 0};
        int j = 0;
        for (; j + 16 <= cnt; j += 16) {
            int2 e0 = cp[j + sub];
            int2 e1 = cp[j + 8 + sub];
            bf16x8 v0 = *(const bf16x8*)(hin + (size_t)e0.x * 256 + fl * 8);
            bf16x8 v1 = *(const bf16x8*)(hin + (size_t)e1.x * 256 + fl * 8);
            float w0 = __int_as_float(e0.y);
            float w1 = __int_as_float(e1.y);
            #pragma unroll
            for (int i = 0; i < 8; i++) a[i] += w0 * b2f_bits(v0[i]);
            #pragma unroll
            for (int i = 0; i < 8; i++) b[i] += w1 * b2f_bits(v1[i]);
        }
        for (; j < cnt; j += 8) {
            int jj = j + sub;
            int2 e = (jj < cnt) ? cp[jj] : make_int2(0, 0);
            bf16x8 v = *(const bf16x8*)(hin + (size_t)e.x * 256 + fl * 8);
            float w = __int_as_float(e.y);
            #pragma unroll
            for (int i = 0; i < 8; i++) a[i] += w * b2f_bits(v[i]);
        }
        #pragma unroll
        for (int i = 0; i < 8; i++) a[i] += b[i];
    }

    #pragma unroll
    for (int i = 0; i < 8; i++) a[i] += __shfl_xor(a[i], 8);
    #pragma unroll
    for (int i = 0; i < 8; i++) a[i] += __shfl_xor(a[i], 16);
    #pragma unroll
    for (int i = 0; i < 8; i++) a[i] += __shfl_xor(a[i], 32);

    if (sub == 0) {
        bf16x8 ov;
        #pragma unroll
        for (int i = 0; i < 8; i++) {
            bf16 t = f2b(a[i] * dr);
            ov[i] = *(short*)&t;
        }
        *(bf16x8*)(hout + (size_t)row * 256 + fl * 8) = ov;
    }
}

// ---------------- fused GEMM: out = H[NN x 256] @ Wcat[256 x 64] + bias ----------------
__global__ __launch_bounds__(256) void gemm_kernel(const bf16* __restrict__ H,
                                                   const bf16* __restrict__ Wt,
                                                   const float* __restrict__ bias,
                                                   float* __restrict__ outb) {
    int row0 = blockIdx.x * 16;
    int wave = threadIdx.x >> 6;
    int lane = threadIdx.x & 63;
    int m = lane & 15, q = lane >> 4;
    int c0 = wave * 16;

    bf16x8 A[8];
    const bf16* arow = H + (size_t)(row0 + m) * 256 + q * 8;
    #pragma unroll
    for (int ks = 0; ks < 8; ks++)
        A[ks] = *(const bf16x8*)(arow + ks * 32);

    const bf16* brow = Wt + (size_t)(c0 + m) * 256 + q * 8;
    f32x4 acc = {0.f, 0.f, 0.f, 0.f};
    #pragma unroll
    for (int ks = 0; ks < 8; ks++) {
        bf16x8 B = *(const bf16x8*)(brow + ks * 32);
        acc = __builtin_amdgcn_mfma_f32_16x16x32_bf16(A[ks], B, acc, 0, 0, 0);
    }

    float bv = bias[c0 + m];
    #pragma unroll
    for (int r = 0; r < 4; r++)
        outb[(size_t)(row0 + q * 4 + r) * 64 + c0 + m] = acc[r] + bv;
}

// ---------------- GraphNorm: single-pass sum+sumsq ----------------
#define CH 32
#define STAT_WAVES ((NN + CH - 1) / CH)
#define STAT_BLOCKS ((STAT_WAVES * 64 + 255) / 256)

__global__ __launch_bounds__(256) void stats_kernel(const float* __restrict__ outb,
                                                    const int* __restrict__ batch,
                                                    float* __restrict__ gsum,
                                                    float* __restrict__ gssq,
                                                    float* __restrict__ gcnt) {
    int wid = (blockIdx.x * 256 + threadIdx.x) >> 6;
    int lane = threadIdx.x & 63;
    int n0 = wid * CH;
    if (n0 >= NN) return;
    int n1 = min(n0 + CH, NN);
    int g0 = batch[n0];
    if (n1 == n0 + CH && batch[n1 - 1] == g0) {
        float s = 0.f, s2 = 0.f;
        #pragma unroll
        for (int i = 0; i < CH; i++) {
            float v = outb[(size_t)(n0 + i) * 64 + lane];
            s += v; s2 += v * v;
        }
        atomicAdd(&gsum[g0 * 64 + lane], s);
        atomicAdd(&gssq[g0 * 64 + lane], s2);
        if (lane == 0) atomicAdd(&gcnt[g0], (float)CH);
    } else {
        int cur = g0; float s = 0.f, s2 = 0.f; int cl = 0;
        for (int i = n0; i < n1; i++) {
            int g = batch[i];
            if (g != cur) {
                atomicAdd(&gsum[cur * 64 + lane], s);
                atomicAdd(&gssq[cur * 64 + lane], s2);
                if (lane == 0) atomicAdd(&gcnt[cur], (float)cl);
                s = 0.f; s2 = 0.f; cl = 0; cur = g;
            }
            float v = outb[(size_t)i * 64 + lane];
            s += v; s2 += v * v; cl++;
        }
        atomicAdd(&gsum[cur * 64 + lane], s);
        atomicAdd(&gssq[cur * 64 + lane], s2);
        if (lane == 0) atomicAdd(&gcnt[cur], (float)cl);
    }
}

__global__ __launch_bounds__(256) void meanrstd_kernel(const float* __restrict__ gsum,
                                                       const float* __restrict__ gssq,
                                                       const float* __restrict__ gcnt,
                                                       const float* __restrict__ gms,
                                                       float* __restrict__ gmean,
                                                       float* __restrict__ grstd) {
    int i = blockIdx.x * 256 + threadIdx.x;
    if (i >= NG * FD) return;
    float c = fmaxf(gcnt[i >> 6], 1.f);
    float mean = gsum[i] / c;
    float msq = gssq[i] / c;
    float mm = mean * gms[i & 63];
    float var = fmaxf(msq - 2.f * mm * mean + mm * mm, 0.f);
    gmean[i] = mean;
    grstd[i] = rsqrtf(var + EPSV);
}

// normalize + residual + relu + write h_emb (nt) + pool accumulation
__global__ __launch_bounds__(256) void final_kernel(const float* __restrict__ outb,
                                                    const int* __restrict__ batch,
                                                    const float* __restrict__ xg,
                                                    const float* __restrict__ gmean,
                                                    const float* __restrict__ grstd,
                                                    const float* __restrict__ gw_,
                                                    const float* __restrict__ gb_,
                                                    const float* __restrict__ ms_,
                                                    float* __restrict__ psum,
                                                    int* __restrict__ pmax,
                                                    float* __restrict__ hemb) {
    int wid = (blockIdx.x * 256 + threadIdx.x) >> 6;
    int lane = threadIdx.x & 63;
    int n0 = wid * CH;
    if (n0 >= NN) return;
    int n1 = min(n0 + CH, NN);
    float gw = gw_[lane], gb = gb_[lane], ms = ms_[lane];
    int g0 = batch[n0];
    if (n1 == n0 + CH && batch[n1 - 1] == g0) {
        float m = gmean[g0 * 64 + lane] * ms;
        float r = grstd[g0 * 64 + lane];
        float ps = 0.f, pm = 0.f;
        #pragma unroll
        for (int i = 0; i < CH; i++) {
            size_t idx = (size_t)(n0 + i) * 64 + lane;
            float hn = gw * (outb[idx] - m) * r + gb;
            float he = hn + xg[idx];
            he = he > 0.f ? he : 0.f;
            __builtin_nontemporal_store(he, &hemb[idx]);
            ps += he;
            pm = fmaxf(pm, he);
        }
        atomicAdd(&psum[g0 * 64 + lane], ps);
        atomicMax(&pmax[g0 * 64 + lane], __float_as_int(pm));
    } else {
        int cur = g0;
        float m = gmean[cur * 64 + lane] * ms;
        float r = grstd[cur * 64 + lane];
        float ps = 0.f, pm = 0.f;
        for (int i = n0; i < n1; i++) {
            int g = batch[i];
            if (g != cur) {
                atomicAdd(&psum[cur * 64 + lane], ps);
                atomicMax(&pmax[cur * 64 + lane], __float_as_int(pm));
                ps = 0.f; pm = 0.f; cur = g;
                m = gmean[cur * 64 + lane] * ms;
                r = grstd[cur * 64 + lane];
            }
            size_t idx = (size_t)i * 64 + lane;
            float hn = gw * (outb[idx] - m) * r + gb;
            float he = hn + xg[idx];
            he = he > 0.f ? he : 0.f;
            __builtin_nontemporal_store(he, &hemb[idx]);
            ps += he;
            pm = fmaxf(pm, he);
        }
        atomicAdd(&psum[cur * 64 + lane], ps);
        atomicMax(&pmax[cur * 64 + lane], __float_as_int(pm));
    }
}

__global__ __launch_bounds__(256) void pool_kernel(const float* __restrict__ psum,
                                                   const int* __restrict__ pmax,
                                                   const float* __restrict__ gcnt,
                                                   float* __restrict__ flat) {
    int i = blockIdx.x * 256 + threadIdx.x;
    if (i >= NG * FD) return;
    int g = i >> 6, f = i & 63;
    float c = fmaxf(gcnt[g], 1.f);
    flat[(size_t)g * 128 + f] = psum[i] / c;
    flat[(size_t)g * 128 + 64 + f] = __int_as_float(pmax[i]);
}

// ---------------- launch ----------------
extern "C" void kernel_launch(void* const* d_in, const int* in_sizes, int n_in,
                              void* d_out, int out_size, void* d_ws, size_t ws_size,
                              hipStream_t stream) {
    const float* x = (const float*)d_in[0];
    const int* ei = (const int*)d_in[1];
    const int* batch = (const int*)d_in[2];
    const float* ew = (const float*)d_in[3];
    const float* W = (const float*)d_in[4];   // [4,64,64]
    const float* bias = (const float*)d_in[5];
    const float* gnw = (const float*)d_in[6];
    const float* gnb = (const float*)d_in[7];
    const float* gms = (const float*)d_in[8];

    const int* src = ei;
    const int* dst = ei + NE;

    char* ws = (char*)d_ws;
    int* cnts = (int*)(ws + OFF_CNT);
    float* gsum = (float*)(ws + OFF_GSUM);
    float* gssq = (float*)(ws + OFF_GSSQ);
    float* gcnt = (float*)(ws + OFF_GCNT);
    float* psum = (float*)(ws + OFF_PSUM);
    int* pmax = (int*)(ws + OFF_PMAX);
    float* gmean = (float*)(ws + OFF_GMEAN);
    float* grstd = (float*)(ws + OFF_GRSTD);
    float* dis = (float*)(ws + OFF_DIS);
    int* rowp = (int*)(ws + OFF_ROWP);
    int* bsum = (int*)(ws + OFF_BSUM);
    bf16* Wt = (bf16*)(ws + OFF_WT);
    int2* csr = (int2*)(ws + OFF_CSR);
    bf16* H = (bf16*)(ws + OFF_H);
    unsigned char* tick = (unsigned char*)(ws + OFF_TICK);  // aliases H; dead before xcopy
    float* outb = (float*)(ws + OFF_OUT);

    float* hemb = (float*)d_out;
    float* flat = hemb + (size_t)NN * FD;

    hipMemsetAsync(d_ws, 0, ZERO_BYTES, stream);

    const int EB = (NE + 255) / 256;
    const int NB = (NN + 255) / 256;
    const int SCB = (NN + 2047) / 2048;
    const int HOPB = (NN + 3) / 4;
    const int GFB = (NG * FD + 255) / 256;

    count_kernel<<<EB, 256, 0, stream>>>(dst, cnts, tick);
    scan_blocks<<<SCB, 256, 0, stream>>>(cnts, rowp, bsum);
    scan_sums<<<1, 64, 0, stream>>>(bsum, SCB);
    scan_add<<<NB, 256, 0, stream>>>(rowp, bsum);
    scatter_kernel<<<EB, 256, 0, stream>>>(src, dst, ew, rowp, tick, csr);
    degdis_kernel<<<NB, 256, 0, stream>>>(rowp, cnts, csr, dis);
    rescale_kernel<<<EB, 256, 0, stream>>>(csr, dis);

    xcopy_kernel<<<(NN * 64 + 255) / 256, 256, 0, stream>>>(x, H);
    wt_kernel<<<64, 256, 0, stream>>>(W, Wt);

    hop_kernel<<<HOPB, 256, 0, stream>>>(H, H + 64, rowp, cnts, csr, dis);        // h1
    hop_kernel<<<HOPB, 256, 0, stream>>>(H + 64, H + 128, rowp, cnts, csr, dis);  // h2
    hop_kernel<<<HOPB, 256, 0, stream>>>(H + 128, H + 192, rowp, cnts, csr, dis); // h3

    gemm_kernel<<<NN / 16, 256, 0, stream>>>(H, Wt, bias, outb);

    stats_kernel<<<STAT_BLOCKS, 256, 0, stream>>>(outb, batch, gsum, gssq, gcnt);
    meanrstd_kernel<<<GFB, 256, 0, stream>>>(gsum, gssq, gcnt, gms, gmean, grstd);
    final_kernel<<<STAT_BLOCKS, 256, 0, stream>>>(outb, batch, x, gmean, grstd, gnw, gnb, gms,
                                                  psum, pmax, hemb);
    pool_kernel<<<GFB, 256, 0, stream>>>(psum, pmax, gcnt, flat);
}

// Round 10
// 454.191 us; speedup vs baseline: 1.0851x; 1.0851x over previous
//
#include <hip/hip_runtime.h>
#include <hip/hip_bf16.h>

// Problem constants (fixed by the reference)
#define NN 100000
#define NE 1600000
#define NG 64
#define FD 64
#define EPSV 1e-5f

typedef __hip_bfloat16 bf16;
typedef __attribute__((ext_vector_type(8))) short bf16x8;  // 8 bf16 = 4 VGPRs (MFMA A/B frag)
typedef __attribute__((ext_vector_type(4))) float f32x4;   // MFMA C/D frag

__device__ __forceinline__ float ldb(bf16 v) { return __bfloat162float(v); }
__device__ __forceinline__ bf16 f2b(float v) { return __float2bfloat16(v); }
__device__ __forceinline__ float b2f_bits(short s) {   // exact bf16 -> fp32
    return __uint_as_float(((unsigned)(unsigned short)s) << 16);
}

// ---------------- workspace layout (bytes) ----------------
// R5/R6: device atomics cost ~32B memory-side traffic each -> ONE atomic pass.
// R9: nt stores on the scatter REGRESS (L2 write-merging coalesces ~16 same-row 8B
// stores into one line writeback) -> plain stores everywhere.
constexpr size_t ALGN(size_t x) { return (x + 255) & ~(size_t)255; }
constexpr size_t OFF_CNT  = 0;                                         // int[NN] (zeroed)
constexpr size_t OFF_GSUM = OFF_CNT  + ALGN((size_t)NN * 4);           // float[NG*FD]
constexpr size_t OFF_GSSQ = OFF_GSUM + ALGN((size_t)NG * FD * 4);      // float[NG*FD]
constexpr size_t OFF_GCNT = OFF_GSSQ + ALGN((size_t)NG * FD * 4);      // float[NG]
constexpr size_t OFF_PSUM = OFF_GCNT + ALGN((size_t)NG * 4);           // float[NG*FD]
constexpr size_t OFF_PMAX = OFF_PSUM + ALGN((size_t)NG * FD * 4);      // int[NG*FD] (relu>=0 so 0-init ok)
constexpr size_t ZERO_BYTES = OFF_PMAX + ALGN((size_t)NG * FD * 4);    // everything above memset(0)
constexpr size_t OFF_DIS   = ZERO_BYTES;                               // float[NN]
constexpr size_t OFF_ROWP  = OFF_DIS   + ALGN((size_t)NN * 4);         // int[NN]
constexpr size_t OFF_BSUM  = OFF_ROWP  + ALGN((size_t)NN * 4);         // int[64] per-block totals
constexpr size_t OFF_WT    = OFF_BSUM  + ALGN(64 * 4);                 // bf16[64][256] W^T stacked
constexpr size_t OFF_CSR   = OFF_WT    + ALGN(16384 * 2);              // int2[NE] {src, w/norm-bits}
constexpr size_t OFF_H     = OFF_CSR   + ALGN((size_t)NE * 8);         // bf16[NN][256]  x|h1|h2|h3
constexpr size_t OFF_TICK  = OFF_H;                                    // u8[NE] ALIAS: dead before xcopy writes H
constexpr size_t OFF_OUT   = OFF_H     + ALGN((size_t)NN * 256 * 2);   // float[NN*FD]

// ---------------- prep kernels ----------------

// ONE atomic per edge; returned old value = unique within-dst ticket (max degree << 255).
__global__ __launch_bounds__(256) void count_kernel(const int* __restrict__ dst,
                                                    int* __restrict__ cnts,
                                                    unsigned char* __restrict__ tick) {
    int e = blockIdx.x * 256 + threadIdx.x;
    if (e >= NE) return;
    tick[e] = (unsigned char)atomicAdd(&cnts[dst[e]], 1);
}

#define SCAN_BLK 256
#define SCAN_ITEMS 8   // 2048 elems per block
__global__ __launch_bounds__(SCAN_BLK) void scan_blocks(const int* __restrict__ cnts,
                                                        int* __restrict__ rowp,
                                                        int* __restrict__ bsum) {
    __shared__ int lds[SCAN_BLK];
    int t = threadIdx.x, b = blockIdx.x;
    int base = b * SCAN_BLK * SCAN_ITEMS + t * SCAN_ITEMS;
    int v[SCAN_ITEMS];
    int s = 0;
    #pragma unroll
    for (int i = 0; i < SCAN_ITEMS; i++) {
        int idx = base + i;
        v[i] = (idx < NN) ? cnts[idx] : 0;
        s += v[i];
    }
    lds[t] = s;
    __syncthreads();
    for (int off = 1; off < SCAN_BLK; off <<= 1) {
        int x = (t >= off) ? lds[t - off] : 0;
        __syncthreads();
        lds[t] += x;
        __syncthreads();
    }
    int excl = lds[t] - s;
    if (t == SCAN_BLK - 1) bsum[b] = lds[t];   // per-block TOTAL (prefix taken in scan_add)
    int run = excl;
    #pragma unroll
    for (int i = 0; i < SCAN_ITEMS; i++) {
        int idx = base + i;
        if (idx < NN) rowp[idx] = run;
        run += v[i];
    }
}

// adds prefix of per-block totals inline (<=49 L2-hot loads/thread) — scan_sums dispatch removed
__global__ __launch_bounds__(256) void scan_add(int* __restrict__ rowp, const int* __restrict__ bsum) {
    int n = blockIdx.x * 256 + threadIdx.x;
    if (n >= NN) return;
    int k = n >> 11;
    int off = 0;
    for (int i = 0; i < k; i++) off += bsum[i];
    rowp[n] += off;
}

// atomic-free scatter: pos = rowp[dst] + tick. Plain store (L2 merges same-row stores).
__global__ __launch_bounds__(256) void scatter_kernel(const int* __restrict__ src,
                                                      const int* __restrict__ dst,
                                                      const float* __restrict__ ew,
                                                      const int* __restrict__ rowp,
                                                      const unsigned char* __restrict__ tick,
                                                      int2* __restrict__ csr) {
    int e = blockIdx.x * 256 + threadIdx.x;
    if (e >= NE) return;
    int d = dst[e];
    int pos = rowp[d] + (int)tick[e];
    csr[pos] = make_int2(src[e], __float_as_int(ew[e]));
}

// deg[n] = sum of raw w over row n (atomic-free, rows contiguous) ; dis = rsqrt
__global__ __launch_bounds__(256) void degdis_kernel(const int* __restrict__ rowp,
                                                     const int* __restrict__ cnts,
                                                     const int2* __restrict__ csr,
                                                     float* __restrict__ dis) {
    int n = blockIdx.x * 256 + threadIdx.x;
    if (n >= NN) return;
    int st = rowp[n], c = cnts[n];
    float s = 0.f;
    for (int j = 0; j < c; j++) s += __int_as_float(csr[st + j].y);
    dis[n] = (s > 0.f) ? rsqrtf(s) : 0.f;
}

// csr.y = w * dis[src]   (coalesced pass; dis is a 400KB L2-resident table)
__global__ __launch_bounds__(256) void rescale_kernel(int2* __restrict__ csr,
                                                      const float* __restrict__ dis) {
    int i = blockIdx.x * 256 + threadIdx.x;
    if (i >= NE) return;
    int2 e = csr[i];
    csr[i].y = __float_as_int(__int_as_float(e.y) * dis[e.x]);
}

// fused: x (fp32) -> H[:,0:64] bf16 (blocks 0..24999) ; W -> Wt bf16 (blocks 25000..25063)
#define XCB 25000
__global__ __launch_bounds__(256) void xcopy_kernel(const float* __restrict__ x,
                                                    bf16* __restrict__ H,
                                                    const float* __restrict__ W,
                                                    bf16* __restrict__ Wt) {
    int b = blockIdx.x;
    if (b < XCB) {
        int i = b * 256 + threadIdx.x;
        if (i >= NN * 64) return;
        int node = i >> 6, f = i & 63;
        H[(size_t)node * 256 + f] = f2b(x[(size_t)node * 64 + f]);
    } else {
        int i = (b - XCB) * 256 + threadIdx.x;   // 0..16383
        int n = i & 63, kk = i >> 6;
        Wt[n * 256 + kk] = f2b(W[kk * 64 + n]);
    }
}

// ---------------- hop: wide-vector gather (R8 structure, proven) ----------------
__global__ __launch_bounds__(256) void hop_kernel(const bf16* __restrict__ hin,  // H + 64*(k-1)
                                                  bf16* __restrict__ hout,       // H + 64*k
                                                  const int* __restrict__ rowp,
                                                  const int* __restrict__ cnts,
                                                  const int2* __restrict__ csr,
                                                  const float* __restrict__ dis) {
    int row = blockIdx.x * 4 + (threadIdx.x >> 6);
    if (row >= NN) return;
    row = __builtin_amdgcn_readfirstlane(row);
    int lane = threadIdx.x & 63;
    int sub = lane >> 3;   // edge slot 0..7
    int fl = lane & 7;     // feature octet 0..7
    int start = rowp[row];
    int cnt = cnts[row];
    float dr = dis[row];
    const int2* cp = csr + start;

    float a[8] = {0, 0, 0, 0, 0, 0, 0, 0};

    if (cnt <= 24) {
        int2 e0 = (sub < cnt) ? cp[sub] : make_int2(0, 0);
        int2 e1 = (8 + sub < cnt) ? cp[8 + sub] : make_int2(0, 0);
        int2 e2 = (16 + sub < cnt) ? cp[16 + sub] : make_int2(0, 0);
        bf16x8 v0 = *(const bf16x8*)(hin + (size_t)e0.x * 256 + fl * 8);
        bf16x8 v1 = *(const bf16x8*)(hin + (size_t)e1.x * 256 + fl * 8);
        bf16x8 v2 = *(const bf16x8*)(hin + (size_t)e2.x * 256 + fl * 8);
        float w0 = __int_as_float(e0.y);
        float w1 = __int_as_float(e1.y);
        float w2 = __int_as_float(e2.y);
        #pragma unroll
        for (int i = 0; i < 8; i++)
            a[i] = w0 * b2f_bits(v0[i]) + w1 * b2f_bits(v1[i]) + w2 * b2f_bits(v2[i]);
    } else {
        float b[8] = {0, 0, 0, 0, 0, 0, 0, 0};
        int j = 0;
        for (; j + 16 <= cnt; j += 16) {
            int2 e0 = cp[j + sub];
            int2 e1 = cp[j + 8 + sub];
            bf16x8 v0 = *(const bf16x8*)(hin + (size_t)e0.x * 256 + fl * 8);
            bf16x8 v1 = *(const bf16x8*)(hin + (size_t)e1.x * 256 + fl * 8);
            float w0 = __int_as_float(e0.y);
            float w1 = __int_as_float(e1.y);
            #pragma unroll
            for (int i = 0; i < 8; i++) a[i] += w0 * b2f_bits(v0[i]);
            #pragma unroll
            for (int i = 0; i < 8; i++) b[i] += w1 * b2f_bits(v1[i]);
        }
        for (; j < cnt; j += 8) {
            int jj = j + sub;
            int2 e = (jj < cnt) ? cp[jj] : make_int2(0, 0);
            bf16x8 v = *(const bf16x8*)(hin + (size_t)e.x * 256 + fl * 8);
            float w = __int_as_float(e.y);
            #pragma unroll
            for (int i = 0; i < 8; i++) a[i] += w * b2f_bits(v[i]);
        }
        #pragma unroll
        for (int i = 0; i < 8; i++) a[i] += b[i];
    }

    #pragma unroll
    for (int i = 0; i < 8; i++) a[i] += __shfl_xor(a[i], 8);
    #pragma unroll
    for (int i = 0; i < 8; i++) a[i] += __shfl_xor(a[i], 16);
    #pragma unroll
    for (int i = 0; i < 8; i++) a[i] += __shfl_xor(a[i], 32);

    if (sub == 0) {
        bf16x8 ov;
        #pragma unroll
        for (int i = 0; i < 8; i++) {
            bf16 t = f2b(a[i] * dr);
            ov[i] = *(short*)&t;
        }
        *(bf16x8*)(hout + (size_t)row * 256 + fl * 8) = ov;
    }
}

// ---------------- fused GEMM: out = H[NN x 256] @ Wcat[256 x 64] + bias ----------------
__global__ __launch_bounds__(256) void gemm_kernel(const bf16* __restrict__ H,
                                                   const bf16* __restrict__ Wt,
                                                   const float* __restrict__ bias,
                                                   float* __restrict__ outb) {
    int row0 = blockIdx.x * 16;
    int wave = threadIdx.x >> 6;
    int lane = threadIdx.x & 63;
    int m = lane & 15, q = lane >> 4;
    int c0 = wave * 16;

    bf16x8 A[8];
    const bf16* arow = H + (size_t)(row0 + m) * 256 + q * 8;
    #pragma unroll
    for (int ks = 0; ks < 8; ks++)
        A[ks] = *(const bf16x8*)(arow + ks * 32);

    const bf16* brow = Wt + (size_t)(c0 + m) * 256 + q * 8;
    f32x4 acc = {0.f, 0.f, 0.f, 0.f};
    #pragma unroll
    for (int ks = 0; ks < 8; ks++) {
        bf16x8 B = *(const bf16x8*)(brow + ks * 32);
        acc = __builtin_amdgcn_mfma_f32_16x16x32_bf16(A[ks], B, acc, 0, 0, 0);
    }

    float bv = bias[c0 + m];
    #pragma unroll
    for (int r = 0; r < 4; r++)
        outb[(size_t)(row0 + q * 4 + r) * 64 + c0 + m] = acc[r] + bv;
}

// ---------------- GraphNorm: single-pass sum+sumsq ----------------
#define CH 32
#define STAT_WAVES ((NN + CH - 1) / CH)
#define STAT_BLOCKS ((STAT_WAVES * 64 + 255) / 256)

__global__ __launch_bounds__(256) void stats_kernel(const float* __restrict__ outb,
                                                    const int* __restrict__ batch,
                                                    float* __restrict__ gsum,
                                                    float* __restrict__ gssq,
                                                    float* __restrict__ gcnt) {
    int wid = (blockIdx.x * 256 + threadIdx.x) >> 6;
    int lane = threadIdx.x & 63;
    int n0 = wid * CH;
    if (n0 >= NN) return;
    int n1 = min(n0 + CH, NN);
    int g0 = batch[n0];
    if (n1 == n0 + CH && batch[n1 - 1] == g0) {
        float s = 0.f, s2 = 0.f;
        #pragma unroll
        for (int i = 0; i < CH; i++) {
            float v = outb[(size_t)(n0 + i) * 64 + lane];
            s += v; s2 += v * v;
        }
        atomicAdd(&gsum[g0 * 64 + lane], s);
        atomicAdd(&gssq[g0 * 64 + lane], s2);
        if (lane == 0) atomicAdd(&gcnt[g0], (float)CH);
    } else {
        int cur = g0; float s = 0.f, s2 = 0.f; int cl = 0;
        for (int i = n0; i < n1; i++) {
            int g = batch[i];
            if (g != cur) {
                atomicAdd(&gsum[cur * 64 + lane], s);
                atomicAdd(&gssq[cur * 64 + lane], s2);
                if (lane == 0) atomicAdd(&gcnt[cur], (float)cl);
                s = 0.f; s2 = 0.f; cl = 0; cur = g;
            }
            float v = outb[(size_t)i * 64 + lane];
            s += v; s2 += v * v; cl++;
        }
        atomicAdd(&gsum[cur * 64 + lane], s);
        atomicAdd(&gssq[cur * 64 + lane], s2);
        if (lane == 0) atomicAdd(&gcnt[cur], (float)cl);
    }
}

// mm/rstd from raw stats (meanrstd fused away): mm = mean*ms; var = E[v^2]-2*mm*E[v]+mm^2
__device__ __forceinline__ void graph_mr(const float* gsum, const float* gssq,
                                         const float* gcnt, int g, int lane, float ms,
                                         float& mm, float& r) {
    float c = fmaxf(gcnt[g], 1.f);
    float mean = gsum[g * 64 + lane] / c;
    float msq = gssq[g * 64 + lane] / c;
    mm = mean * ms;
    float var = fmaxf(msq - 2.f * mm * mean + mm * mm, 0.f);
    r = rsqrtf(var + EPSV);
}

// normalize + residual + relu + write h_emb + pool accumulation
__global__ __launch_bounds__(256) void final_kernel(const float* __restrict__ outb,
                                                    const int* __restrict__ batch,
                                                    const float* __restrict__ xg,
                                                    const float* __restrict__ gsum,
                                                    const float* __restrict__ gssq,
                                                    const float* __restrict__ gcnt,
                                                    const float* __restrict__ gw_,
                                                    const float* __restrict__ gb_,
                                                    const float* __restrict__ ms_,
                                                    float* __restrict__ psum,
                                                    int* __restrict__ pmax,
                                                    float* __restrict__ hemb) {
    int wid = (blockIdx.x * 256 + threadIdx.x) >> 6;
    int lane = threadIdx.x & 63;
    int n0 = wid * CH;
    if (n0 >= NN) return;
    int n1 = min(n0 + CH, NN);
    float gw = gw_[lane], gb = gb_[lane], ms = ms_[lane];
    int g0 = batch[n0];
    if (n1 == n0 + CH && batch[n1 - 1] == g0) {
        float m, r;
        graph_mr(gsum, gssq, gcnt, g0, lane, ms, m, r);
        float ps = 0.f, pm = 0.f;
        #pragma unroll
        for (int i = 0; i < CH; i++) {
            size_t idx = (size_t)(n0 + i) * 64 + lane;
            float hn = gw * (outb[idx] - m) * r + gb;
            float he = hn + xg[idx];
            he = he > 0.f ? he : 0.f;
            hemb[idx] = he;
            ps += he;
            pm = fmaxf(pm, he);
        }
        atomicAdd(&psum[g0 * 64 + lane], ps);
        atomicMax(&pmax[g0 * 64 + lane], __float_as_int(pm));
    } else {
        int cur = g0;
        float m, r;
        graph_mr(gsum, gssq, gcnt, cur, lane, ms, m, r);
        float ps = 0.f, pm = 0.f;
        for (int i = n0; i < n1; i++) {
            int g = batch[i];
            if (g != cur) {
                atomicAdd(&psum[cur * 64 + lane], ps);
                atomicMax(&pmax[cur * 64 + lane], __float_as_int(pm));
                ps = 0.f; pm = 0.f; cur = g;
                graph_mr(gsum, gssq, gcnt, cur, lane, ms, m, r);
            }
            size_t idx = (size_t)i * 64 + lane;
            float hn = gw * (outb[idx] - m) * r + gb;
            float he = hn + xg[idx];
            he = he > 0.f ? he : 0.f;
            hemb[idx] = he;
            ps += he;
            pm = fmaxf(pm, he);
        }
        atomicAdd(&psum[cur * 64 + lane], ps);
        atomicMax(&pmax[cur * 64 + lane], __float_as_int(pm));
    }
}

__global__ __launch_bounds__(256) void pool_kernel(const float* __restrict__ psum,
                                                   const int* __restrict__ pmax,
                                                   const float* __restrict__ gcnt,
                                                   float* __restrict__ flat) {
    int i = blockIdx.x * 256 + threadIdx.x;
    if (i >= NG * FD) return;
    int g = i >> 6, f = i & 63;
    float c = fmaxf(gcnt[g], 1.f);
    flat[(size_t)g * 128 + f] = psum[i] / c;
    flat[(size_t)g * 128 + 64 + f] = __int_as_float(pmax[i]);
}

// ---------------- launch ----------------
extern "C" void kernel_launch(void* const* d_in, const int* in_sizes, int n_in,
                              void* d_out, int out_size, void* d_ws, size_t ws_size,
                              hipStream_t stream) {
    const float* x = (const float*)d_in[0];
    const int* ei = (const int*)d_in[1];
    const int* batch = (const int*)d_in[2];
    const float* ew = (const float*)d_in[3];
    const float* W = (const float*)d_in[4];   // [4,64,64]
    const float* bias = (const float*)d_in[5];
    const float* gnw = (const float*)d_in[6];
    const float* gnb = (const float*)d_in[7];
    const float* gms = (const float*)d_in[8];

    const int* src = ei;
    const int* dst = ei + NE;

    char* ws = (char*)d_ws;
    int* cnts = (int*)(ws + OFF_CNT);
    float* gsum = (float*)(ws + OFF_GSUM);
    float* gssq = (float*)(ws + OFF_GSSQ);
    float* gcnt = (float*)(ws + OFF_GCNT);
    float* psum = (float*)(ws + OFF_PSUM);
    int* pmax = (int*)(ws + OFF_PMAX);
    float* dis = (float*)(ws + OFF_DIS);
    int* rowp = (int*)(ws + OFF_ROWP);
    int* bsum = (int*)(ws + OFF_BSUM);
    bf16* Wt = (bf16*)(ws + OFF_WT);
    int2* csr = (int2*)(ws + OFF_CSR);
    bf16* H = (bf16*)(ws + OFF_H);
    unsigned char* tick = (unsigned char*)(ws + OFF_TICK);  // aliases H; dead before xcopy
    float* outb = (float*)(ws + OFF_OUT);

    float* hemb = (float*)d_out;
    float* flat = hemb + (size_t)NN * FD;

    hipMemsetAsync(d_ws, 0, ZERO_BYTES, stream);

    const int EB = (NE + 255) / 256;
    const int NB = (NN + 255) / 256;
    const int SCB = (NN + 2047) / 2048;
    const int HOPB = (NN + 3) / 4;
    const int GFB = (NG * FD + 255) / 256;

    count_kernel<<<EB, 256, 0, stream>>>(dst, cnts, tick);
    scan_blocks<<<SCB, 256, 0, stream>>>(cnts, rowp, bsum);
    scan_add<<<NB, 256, 0, stream>>>(rowp, bsum);
    scatter_kernel<<<EB, 256, 0, stream>>>(src, dst, ew, rowp, tick, csr);
    degdis_kernel<<<NB, 256, 0, stream>>>(rowp, cnts, csr, dis);
    rescale_kernel<<<EB, 256, 0, stream>>>(csr, dis);

    xcopy_kernel<<<XCB + 64, 256, 0, stream>>>(x, H, W, Wt);

    hop_kernel<<<HOPB, 256, 0, stream>>>(H, H + 64, rowp, cnts, csr, dis);        // h1
    hop_kernel<<<HOPB, 256, 0, stream>>>(H + 64, H + 128, rowp, cnts, csr, dis);  // h2
    hop_kernel<<<HOPB, 256, 0, stream>>>(H + 128, H + 192, rowp, cnts, csr, dis); // h3

    gemm_kernel<<<NN / 16, 256, 0, stream>>>(H, Wt, bias, outb);

    stats_kernel<<<STAT_BLOCKS, 256, 0, stream>>>(outb, batch, gsum, gssq, gcnt);
    final_kernel<<<STAT_BLOCKS, 256, 0, stream>>>(outb, batch, x, gsum, gssq, gcnt,
                                                  gnw, gnb, gms, psum, pmax, hemb);
    pool_kernel<<<GFB, 256, 0, stream>>>(psum, pmax, gcnt, flat);
}

// Round 11
// 443.128 us; speedup vs baseline: 1.1122x; 1.0250x over previous
//
#include <hip/hip_runtime.h>
#include <hip/hip_bf16.h>

// Problem constants (fixed by the reference)
#define NN 100000
#define NE 1600000
#define NG 64
#define FD 64
#define EPSV 1e-5f

typedef __hip_bfloat16 bf16;
typedef __attribute__((ext_vector_type(8))) short bf16x8;  // 8 bf16 = 4 VGPRs (MFMA A/B frag)
typedef __attribute__((ext_vector_type(4))) float f32x4;   // MFMA C/D frag

__device__ __forceinline__ float ldb(bf16 v) { return __bfloat162float(v); }
__device__ __forceinline__ bf16 f2b(float v) { return __float2bfloat16(v); }
__device__ __forceinline__ float b2f_bits(short s) {   // exact bf16 -> fp32
    return __uint_as_float(((unsigned)(unsigned short)s) << 16);
}

// ---------------- workspace layout (bytes) ----------------
// R5/R6: device atomics ~32B memory-side traffic each -> ONE atomic pass.
// R9: nt stores regress (L2 write-merging). R11: tick gets its OWN region (count is
// fused with xcopy, so tick can no longer alias H); rescale pass removed (hop1 bakes
// dis[src] into csr.y and writes back).
constexpr size_t ALGN(size_t x) { return (x + 255) & ~(size_t)255; }
constexpr size_t OFF_CNT  = 0;                                         // int[NN] (zeroed)
constexpr size_t OFF_GSUM = OFF_CNT  + ALGN((size_t)NN * 4);           // float[NG*FD]
constexpr size_t OFF_GSSQ = OFF_GSUM + ALGN((size_t)NG * FD * 4);      // float[NG*FD]
constexpr size_t OFF_GCNT = OFF_GSSQ + ALGN((size_t)NG * FD * 4);      // float[NG]
constexpr size_t OFF_PSUM = OFF_GCNT + ALGN((size_t)NG * 4);           // float[NG*FD]
constexpr size_t OFF_PMAX = OFF_PSUM + ALGN((size_t)NG * FD * 4);      // int[NG*FD] (relu>=0 so 0-init ok)
constexpr size_t ZERO_BYTES = OFF_PMAX + ALGN((size_t)NG * FD * 4);    // everything above memset(0)
constexpr size_t OFF_DIS   = ZERO_BYTES;                               // float[NN]
constexpr size_t OFF_ROWP  = OFF_DIS   + ALGN((size_t)NN * 4);         // int[NN]
constexpr size_t OFF_BSUM  = OFF_ROWP  + ALGN((size_t)NN * 4);         // int[64] per-block totals
constexpr size_t OFF_WT    = OFF_BSUM  + ALGN(64 * 4);                 // bf16[64][256] W^T stacked
constexpr size_t OFF_TICK  = OFF_WT    + ALGN(16384 * 2);              // u8[NE] (own region now)
constexpr size_t OFF_CSR   = OFF_TICK  + ALGN((size_t)NE);             // int2[NE] {src, w/norm-bits}
constexpr size_t OFF_H     = OFF_CSR   + ALGN((size_t)NE * 8);         // bf16[NN][256]  x|h1|h2|h3
constexpr size_t OFF_OUT   = OFF_H     + ALGN((size_t)NN * 256 * 2);   // float[NN*FD]

// ---------------- fused prep: count (atomic-bound) + xcopy/wt (streaming) ----------------
// count blocks are atomic-transaction-bound at 0.4% VALUBusy / ~840 GB/s; the xcopy/wt
// blocks stream on otherwise-idle HBM capacity and hide inside count's runtime.
#define EB ((NE + 255) / 256)
#define XCB 25000
__global__ __launch_bounds__(256) void count_fused_kernel(const int* __restrict__ dst,
                                                          int* __restrict__ cnts,
                                                          unsigned char* __restrict__ tick,
                                                          const float* __restrict__ x,
                                                          bf16* __restrict__ H,
                                                          const float* __restrict__ W,
                                                          bf16* __restrict__ Wt) {
    int b = blockIdx.x;
    if (b < EB) {
        int e = b * 256 + threadIdx.x;
        if (e >= NE) return;
        tick[e] = (unsigned char)atomicAdd(&cnts[dst[e]], 1);
    } else if (b < EB + XCB) {
        int i = (b - EB) * 256 + threadIdx.x;
        if (i >= NN * 64) return;
        int node = i >> 6, f = i & 63;
        H[(size_t)node * 256 + f] = f2b(x[(size_t)node * 64 + f]);
    } else {
        int i = (b - EB - XCB) * 256 + threadIdx.x;  // 0..16383
        int n = i & 63, kk = i >> 6;
        Wt[n * 256 + kk] = f2b(W[kk * 64 + n]);
    }
}

#define SCAN_BLK 256
#define SCAN_ITEMS 8   // 2048 elems per block
__global__ __launch_bounds__(SCAN_BLK) void scan_blocks(const int* __restrict__ cnts,
                                                        int* __restrict__ rowp,
                                                        int* __restrict__ bsum) {
    __shared__ int lds[SCAN_BLK];
    int t = threadIdx.x, b = blockIdx.x;
    int base = b * SCAN_BLK * SCAN_ITEMS + t * SCAN_ITEMS;
    int v[SCAN_ITEMS];
    int s = 0;
    #pragma unroll
    for (int i = 0; i < SCAN_ITEMS; i++) {
        int idx = base + i;
        v[i] = (idx < NN) ? cnts[idx] : 0;
        s += v[i];
    }
    lds[t] = s;
    __syncthreads();
    for (int off = 1; off < SCAN_BLK; off <<= 1) {
        int x = (t >= off) ? lds[t - off] : 0;
        __syncthreads();
        lds[t] += x;
        __syncthreads();
    }
    int excl = lds[t] - s;
    if (t == SCAN_BLK - 1) bsum[b] = lds[t];   // per-block TOTAL (prefix taken in scan_add)
    int run = excl;
    #pragma unroll
    for (int i = 0; i < SCAN_ITEMS; i++) {
        int idx = base + i;
        if (idx < NN) rowp[idx] = run;
        run += v[i];
    }
}

// adds prefix of per-block totals inline (<=49 L2-hot loads/thread)
__global__ __launch_bounds__(256) void scan_add(int* __restrict__ rowp, const int* __restrict__ bsum) {
    int n = blockIdx.x * 256 + threadIdx.x;
    if (n >= NN) return;
    int k = n >> 11;
    int off = 0;
    for (int i = 0; i < k; i++) off += bsum[i];
    rowp[n] += off;
}

// atomic-free scatter: pos = rowp[dst] + tick. Plain store (L2 merges same-row stores).
__global__ __launch_bounds__(256) void scatter_kernel(const int* __restrict__ src,
                                                      const int* __restrict__ dst,
                                                      const float* __restrict__ ew,
                                                      const int* __restrict__ rowp,
                                                      const unsigned char* __restrict__ tick,
                                                      int2* __restrict__ csr) {
    int e = blockIdx.x * 256 + threadIdx.x;
    if (e >= NE) return;
    int d = dst[e];
    int pos = rowp[d] + (int)tick[e];
    csr[pos] = make_int2(src[e], __float_as_int(ew[e]));
}

// deg[n] = sum of raw w over row n (atomic-free, rows contiguous) ; dis = rsqrt
__global__ __launch_bounds__(256) void degdis_kernel(const int* __restrict__ rowp,
                                                     const int* __restrict__ cnts,
                                                     const int2* __restrict__ csr,
                                                     float* __restrict__ dis) {
    int n = blockIdx.x * 256 + threadIdx.x;
    if (n >= NN) return;
    int st = rowp[n], c = cnts[n];
    float s = 0.f;
    for (int j = 0; j < c; j++) s += __int_as_float(csr[st + j].y);
    dis[n] = (s > 0.f) ? rsqrtf(s) : 0.f;
}

// ---------------- hop: wide-vector gather (R8 structure) ----------------
// FIRST: csr.y holds RAW w -> gather dis[e.x] (400KB L2-hot; 8 contiguous lanes share
// each address), nr = w*dis[src], write nr back so hops 2/3 read pre-scaled (replaces
// the 19MB rescale pass; cross-dispatch visibility via kernel-boundary release/acquire).
template <bool FIRST>
__global__ __launch_bounds__(256) void hop_kernel(const bf16* __restrict__ hin,  // H + 64*(k-1)
                                                  bf16* __restrict__ hout,       // H + 64*k
                                                  const int* __restrict__ rowp,
                                                  const int* __restrict__ cnts,
                                                  int2* __restrict__ csr,
                                                  const float* __restrict__ dis) {
    int row = blockIdx.x * 4 + (threadIdx.x >> 6);
    if (row >= NN) return;
    row = __builtin_amdgcn_readfirstlane(row);
    int lane = threadIdx.x & 63;
    int sub = lane >> 3;   // edge slot 0..7
    int fl = lane & 7;     // feature octet 0..7
    int start = rowp[row];
    int cnt = cnts[row];
    float dr = dis[row];
    int2* cp = csr + start;

    float a[8] = {0, 0, 0, 0, 0, 0, 0, 0};

    if (cnt <= 24) {
        int2 e0 = (sub < cnt) ? cp[sub] : make_int2(0, 0);
        int2 e1 = (8 + sub < cnt) ? cp[8 + sub] : make_int2(0, 0);
        int2 e2 = (16 + sub < cnt) ? cp[16 + sub] : make_int2(0, 0);
        bf16x8 v0 = *(const bf16x8*)(hin + (size_t)e0.x * 256 + fl * 8);
        bf16x8 v1 = *(const bf16x8*)(hin + (size_t)e1.x * 256 + fl * 8);
        bf16x8 v2 = *(const bf16x8*)(hin + (size_t)e2.x * 256 + fl * 8);
        float w0 = __int_as_float(e0.y);
        float w1 = __int_as_float(e1.y);
        float w2 = __int_as_float(e2.y);
        if (FIRST) {
            w0 *= dis[e0.x]; w1 *= dis[e1.x]; w2 *= dis[e2.x];
            if (fl == 0) {
                if (sub < cnt)      cp[sub].y      = __float_as_int(w0);
                if (8 + sub < cnt)  cp[8 + sub].y  = __float_as_int(w1);
                if (16 + sub < cnt) cp[16 + sub].y = __float_as_int(w2);
            }
        }
        #pragma unroll
        for (int i = 0; i < 8; i++)
            a[i] = w0 * b2f_bits(v0[i]) + w1 * b2f_bits(v1[i]) + w2 * b2f_bits(v2[i]);
    } else {
        float b[8] = {0, 0, 0, 0, 0, 0, 0, 0};
        int j = 0;
        for (; j + 16 <= cnt; j += 16) {
            int2 e0 = cp[j + sub];
            int2 e1 = cp[j + 8 + sub];
            bf16x8 v0 = *(const bf16x8*)(hin + (size_t)e0.x * 256 + fl * 8);
            bf16x8 v1 = *(const bf16x8*)(hin + (size_t)e1.x * 256 + fl * 8);
            float w0 = __int_as_float(e0.y);
            float w1 = __int_as_float(e1.y);
            if (FIRST) {
                w0 *= dis[e0.x]; w1 *= dis[e1.x];
                if (fl == 0) {
                    cp[j + sub].y     = __float_as_int(w0);
                    cp[j + 8 + sub].y = __float_as_int(w1);
                }
            }
            #pragma unroll
            for (int i = 0; i < 8; i++) a[i] += w0 * b2f_bits(v0[i]);
            #pragma unroll
            for (int i = 0; i < 8; i++) b[i] += w1 * b2f_bits(v1[i]);
        }
        for (; j < cnt; j += 8) {
            int jj = j + sub;
            int2 e = (jj < cnt) ? cp[jj] : make_int2(0, 0);
            bf16x8 v = *(const bf16x8*)(hin + (size_t)e.x * 256 + fl * 8);
            float w = __int_as_float(e.y);
            if (FIRST) {
                w *= dis[e.x];
                if (fl == 0 && jj < cnt) cp[jj].y = __float_as_int(w);
            }
            #pragma unroll
            for (int i = 0; i < 8; i++) a[i] += w * b2f_bits(v[i]);
        }
        #pragma unroll
        for (int i = 0; i < 8; i++) a[i] += b[i];
    }

    #pragma unroll
    for (int i = 0; i < 8; i++) a[i] += __shfl_xor(a[i], 8);
    #pragma unroll
    for (int i = 0; i < 8; i++) a[i] += __shfl_xor(a[i], 16);
    #pragma unroll
    for (int i = 0; i < 8; i++) a[i] += __shfl_xor(a[i], 32);

    if (sub == 0) {
        bf16x8 ov;
        #pragma unroll
        for (int i = 0; i < 8; i++) {
            bf16 t = f2b(a[i] * dr);
            ov[i] = *(short*)&t;
        }
        *(bf16x8*)(hout + (size_t)row * 256 + fl * 8) = ov;
    }
}

// ---------------- fused GEMM: out = H[NN x 256] @ Wcat[256 x 64] + bias ----------------
__global__ __launch_bounds__(256) void gemm_kernel(const bf16* __restrict__ H,
                                                   const bf16* __restrict__ Wt,
                                                   const float* __restrict__ bias,
                                                   float* __restrict__ outb) {
    int row0 = blockIdx.x * 16;
    int wave = threadIdx.x >> 6;
    int lane = threadIdx.x & 63;
    int m = lane & 15, q = lane >> 4;
    int c0 = wave * 16;

    bf16x8 A[8];
    const bf16* arow = H + (size_t)(row0 + m) * 256 + q * 8;
    #pragma unroll
    for (int ks = 0; ks < 8; ks++)
        A[ks] = *(const bf16x8*)(arow + ks * 32);

    const bf16* brow = Wt + (size_t)(c0 + m) * 256 + q * 8;
    f32x4 acc = {0.f, 0.f, 0.f, 0.f};
    #pragma unroll
    for (int ks = 0; ks < 8; ks++) {
        bf16x8 B = *(const bf16x8*)(brow + ks * 32);
        acc = __builtin_amdgcn_mfma_f32_16x16x32_bf16(A[ks], B, acc, 0, 0, 0);
    }

    float bv = bias[c0 + m];
    #pragma unroll
    for (int r = 0; r < 4; r++)
        outb[(size_t)(row0 + q * 4 + r) * 64 + c0 + m] = acc[r] + bv;
}

// ---------------- GraphNorm: single-pass sum+sumsq ----------------
#define CH 32
#define STAT_WAVES ((NN + CH - 1) / CH)
#define STAT_BLOCKS ((STAT_WAVES * 64 + 255) / 256)

__global__ __launch_bounds__(256) void stats_kernel(const float* __restrict__ outb,
                                                    const int* __restrict__ batch,
                                                    float* __restrict__ gsum,
                                                    float* __restrict__ gssq,
                                                    float* __restrict__ gcnt) {
    int wid = (blockIdx.x * 256 + threadIdx.x) >> 6;
    int lane = threadIdx.x & 63;
    int n0 = wid * CH;
    if (n0 >= NN) return;
    int n1 = min(n0 + CH, NN);
    int g0 = batch[n0];
    if (n1 == n0 + CH && batch[n1 - 1] == g0) {
        float s = 0.f, s2 = 0.f;
        #pragma unroll
        for (int i = 0; i < CH; i++) {
            float v = outb[(size_t)(n0 + i) * 64 + lane];
            s += v; s2 += v * v;
        }
        atomicAdd(&gsum[g0 * 64 + lane], s);
        atomicAdd(&gssq[g0 * 64 + lane], s2);
        if (lane == 0) atomicAdd(&gcnt[g0], (float)CH);
    } else {
        int cur = g0; float s = 0.f, s2 = 0.f; int cl = 0;
        for (int i = n0; i < n1; i++) {
            int g = batch[i];
            if (g != cur) {
                atomicAdd(&gsum[cur * 64 + lane], s);
                atomicAdd(&gssq[cur * 64 + lane], s2);
                if (lane == 0) atomicAdd(&gcnt[cur], (float)cl);
                s = 0.f; s2 = 0.f; cl = 0; cur = g;
            }
            float v = outb[(size_t)i * 64 + lane];
            s += v; s2 += v * v; cl++;
        }
        atomicAdd(&gsum[cur * 64 + lane], s);
        atomicAdd(&gssq[cur * 64 + lane], s2);
        if (lane == 0) atomicAdd(&gcnt[cur], (float)cl);
    }
}

// mm/rstd from raw stats: mm = mean*ms; var = E[v^2]-2*mm*E[v]+mm^2
__device__ __forceinline__ void graph_mr(const float* gsum, const float* gssq,
                                         const float* gcnt, int g, int lane, float ms,
                                         float& mm, float& r) {
    float c = fmaxf(gcnt[g], 1.f);
    float mean = gsum[g * 64 + lane] / c;
    float msq = gssq[g * 64 + lane] / c;
    mm = mean * ms;
    float var = fmaxf(msq - 2.f * mm * mean + mm * mm, 0.f);
    r = rsqrtf(var + EPSV);
}

// normalize + residual + relu + write h_emb + pool accumulation
__global__ __launch_bounds__(256) void final_kernel(const float* __restrict__ outb,
                                                    const int* __restrict__ batch,
                                                    const float* __restrict__ xg,
                                                    const float* __restrict__ gsum,
                                                    const float* __restrict__ gssq,
                                                    const float* __restrict__ gcnt,
                                                    const float* __restrict__ gw_,
                                                    const float* __restrict__ gb_,
                                                    const float* __restrict__ ms_,
                                                    float* __restrict__ psum,
                                                    int* __restrict__ pmax,
                                                    float* __restrict__ hemb) {
    int wid = (blockIdx.x * 256 + threadIdx.x) >> 6;
    int lane = threadIdx.x & 63;
    int n0 = wid * CH;
    if (n0 >= NN) return;
    int n1 = min(n0 + CH, NN);
    float gw = gw_[lane], gb = gb_[lane], ms = ms_[lane];
    int g0 = batch[n0];
    if (n1 == n0 + CH && batch[n1 - 1] == g0) {
        float m, r;
        graph_mr(gsum, gssq, gcnt, g0, lane, ms, m, r);
        float ps = 0.f, pm = 0.f;
        #pragma unroll
        for (int i = 0; i < CH; i++) {
            size_t idx = (size_t)(n0 + i) * 64 + lane;
            float hn = gw * (outb[idx] - m) * r + gb;
            float he = hn + xg[idx];
            he = he > 0.f ? he : 0.f;
            hemb[idx] = he;
            ps += he;
            pm = fmaxf(pm, he);
        }
        atomicAdd(&psum[g0 * 64 + lane], ps);
        atomicMax(&pmax[g0 * 64 + lane], __float_as_int(pm));
    } else {
        int cur = g0;
        float m, r;
        graph_mr(gsum, gssq, gcnt, cur, lane, ms, m, r);
        float ps = 0.f, pm = 0.f;
        for (int i = n0; i < n1; i++) {
            int g = batch[i];
            if (g != cur) {
                atomicAdd(&psum[cur * 64 + lane], ps);
                atomicMax(&pmax[cur * 64 + lane], __float_as_int(pm));
                ps = 0.f; pm = 0.f; cur = g;
                graph_mr(gsum, gssq, gcnt, cur, lane, ms, m, r);
            }
            size_t idx = (size_t)i * 64 + lane;
            float hn = gw * (outb[idx] - m) * r + gb;
            float he = hn + xg[idx];
            he = he > 0.f ? he : 0.f;
            hemb[idx] = he;
            ps += he;
            pm = fmaxf(pm, he);
        }
        atomicAdd(&psum[cur * 64 + lane], ps);
        atomicMax(&pmax[cur * 64 + lane], __float_as_int(pm));
    }
}

__global__ __launch_bounds__(256) void pool_kernel(const float* __restrict__ psum,
                                                   const int* __restrict__ pmax,
                                                   const float* __restrict__ gcnt,
                                                   float* __restrict__ flat) {
    int i = blockIdx.x * 256 + threadIdx.x;
    if (i >= NG * FD) return;
    int g = i >> 6, f = i & 63;
    float c = fmaxf(gcnt[g], 1.f);
    flat[(size_t)g * 128 + f] = psum[i] / c;
    flat[(size_t)g * 128 + 64 + f] = __int_as_float(pmax[i]);
}

// ---------------- launch ----------------
extern "C" void kernel_launch(void* const* d_in, const int* in_sizes, int n_in,
                              void* d_out, int out_size, void* d_ws, size_t ws_size,
                              hipStream_t stream) {
    const float* x = (const float*)d_in[0];
    const int* ei = (const int*)d_in[1];
    const int* batch = (const int*)d_in[2];
    const float* ew = (const float*)d_in[3];
    const float* W = (const float*)d_in[4];   // [4,64,64]
    const float* bias = (const float*)d_in[5];
    const float* gnw = (const float*)d_in[6];
    const float* gnb = (const float*)d_in[7];
    const float* gms = (const float*)d_in[8];

    const int* src = ei;
    const int* dst = ei + NE;

    char* ws = (char*)d_ws;
    int* cnts = (int*)(ws + OFF_CNT);
    float* gsum = (float*)(ws + OFF_GSUM);
    float* gssq = (float*)(ws + OFF_GSSQ);
    float* gcnt = (float*)(ws + OFF_GCNT);
    float* psum = (float*)(ws + OFF_PSUM);
    int* pmax = (int*)(ws + OFF_PMAX);
    float* dis = (float*)(ws + OFF_DIS);
    int* rowp = (int*)(ws + OFF_ROWP);
    int* bsum = (int*)(ws + OFF_BSUM);
    bf16* Wt = (bf16*)(ws + OFF_WT);
    unsigned char* tick = (unsigned char*)(ws + OFF_TICK);
    int2* csr = (int2*)(ws + OFF_CSR);
    bf16* H = (bf16*)(ws + OFF_H);
    float* outb = (float*)(ws + OFF_OUT);

    float* hemb = (float*)d_out;
    float* flat = hemb + (size_t)NN * FD;

    hipMemsetAsync(d_ws, 0, ZERO_BYTES, stream);

    const int NB = (NN + 255) / 256;
    const int SCB = (NN + 2047) / 2048;
    const int HOPB = (NN + 3) / 4;
    const int GFB = (NG * FD + 255) / 256;

    count_fused_kernel<<<EB + XCB + 64, 256, 0, stream>>>(dst, cnts, tick, x, H, W, Wt);
    scan_blocks<<<SCB, 256, 0, stream>>>(cnts, rowp, bsum);
    scan_add<<<NB, 256, 0, stream>>>(rowp, bsum);
    scatter_kernel<<<EB, 256, 0, stream>>>(src, dst, ew, rowp, tick, csr);
    degdis_kernel<<<NB, 256, 0, stream>>>(rowp, cnts, csr, dis);

    hop_kernel<true><<<HOPB, 256, 0, stream>>>(H, H + 64, rowp, cnts, csr, dis);         // h1 (+rescale)
    hop_kernel<false><<<HOPB, 256, 0, stream>>>(H + 64, H + 128, rowp, cnts, csr, dis);  // h2
    hop_kernel<false><<<HOPB, 256, 0, stream>>>(H + 128, H + 192, rowp, cnts, csr, dis); // h3

    gemm_kernel<<<NN / 16, 256, 0, stream>>>(H, Wt, bias, outb);

    stats_kernel<<<STAT_BLOCKS, 256, 0, stream>>>(outb, batch, gsum, gssq, gcnt);
    final_kernel<<<STAT_BLOCKS, 256, 0, stream>>>(outb, batch, x, gsum, gssq, gcnt,
                                                  gnw, gnb, gms, psum, pmax, hemb);
    pool_kernel<<<GFB, 256, 0, stream>>>(psum, pmax, gcnt, flat);
}